// Round 1
// baseline (2895.228 us; speedup 1.0000x reference)
//
#include <hip/hip_runtime.h>
#include <math.h>

#define NFEAT 512
#define NHID  256
#define NCLS  64
#define KHOP  10

// ---------------- GEMM: C = act(A@W + bias), optional hidden init epilogue ----
#define BM 64
#define BN 64
#define BK 32

template<int EPI>  // EPI=0: relu;  EPI=1: plain bias + hidden = temp[0]*val
__global__ __launch_bounds__(256) void gemm_kernel(
    const float* __restrict__ A, const float* __restrict__ W,
    const float* __restrict__ bias, float* __restrict__ C,
    int M, int N, int K,
    float* __restrict__ hidden, const float* __restrict__ temp)
{
    __shared__ float As[BK][BM + 4];
    __shared__ float Bs[BK][BN + 4];
    const int tid = threadIdx.x;
    const int bm = blockIdx.x * BM, bn = blockIdx.y * BN;
    const int tx = tid & 15, ty = tid >> 4;

    float acc[4][4] = {{0.f,0.f,0.f,0.f},{0.f,0.f,0.f,0.f},
                       {0.f,0.f,0.f,0.f},{0.f,0.f,0.f,0.f}};

    const int ar = tid >> 3;          // 0..31
    const int ak = (tid & 7) << 2;    // 0,4,...,28
    const int br = tid >> 4;          // 0..15
    const int bc = (tid & 15) << 2;   // 0,4,...,60

    for (int k0 = 0; k0 < K; k0 += BK) {
        #pragma unroll
        for (int i = 0; i < 2; i++) {
            int row = bm + ar + i * 32;
            float4 v = make_float4(0.f, 0.f, 0.f, 0.f);
            if (row < M) v = *(const float4*)(A + (long)row * K + k0 + ak);
            As[ak + 0][ar + i * 32] = v.x;
            As[ak + 1][ar + i * 32] = v.y;
            As[ak + 2][ar + i * 32] = v.z;
            As[ak + 3][ar + i * 32] = v.w;
        }
        #pragma unroll
        for (int i = 0; i < 2; i++) {
            int kr = k0 + br + i * 16;
            *(float4*)&Bs[br + i * 16][bc] = *(const float4*)(W + (long)kr * N + bn + bc);
        }
        __syncthreads();
        #pragma unroll
        for (int kk = 0; kk < BK; kk++) {
            float4 a = *(const float4*)&As[kk][ty << 2];
            float4 b = *(const float4*)&Bs[kk][tx << 2];
            float av[4] = {a.x, a.y, a.z, a.w};
            float bv[4] = {b.x, b.y, b.z, b.w};
            #pragma unroll
            for (int i = 0; i < 4; i++)
                #pragma unroll
                for (int j = 0; j < 4; j++)
                    acc[i][j] = fmaf(av[i], bv[j], acc[i][j]);
        }
        __syncthreads();
    }

    #pragma unroll
    for (int i = 0; i < 4; i++) {
        int row = bm + (ty << 2) + i;
        if (row >= M) continue;
        #pragma unroll
        for (int j = 0; j < 4; j++) {
            int col = bn + (tx << 2) + j;
            float v = acc[i][j] + bias[col];
            if (EPI == 0) {
                C[(long)row * N + col] = fmaxf(v, 0.f);
            } else {
                C[(long)row * N + col] = v;
                hidden[(long)row * N + col] = temp[0] * v;
            }
        }
    }
}

// ---------------- graph preprocessing ----------------
__global__ void count_kernel(const int* __restrict__ ei, int E, int* __restrict__ cnt)
{
    int e = blockIdx.x * blockDim.x + threadIdx.x;
    if (e < E) atomicAdd(&cnt[ei[E + e]], 1);   // col = destination
}

__global__ void dis_kernel(const int* __restrict__ cnt, float* __restrict__ dis, int Nn)
{
    int v = blockIdx.x * blockDim.x + threadIdx.x;
    if (v < Nn) dis[v] = rsqrtf((float)(cnt[v] + 1));   // +1 self loop, always > 0
}

__global__ __launch_bounds__(1024) void scan_kernel(const int* __restrict__ cnt,
                                                    int* __restrict__ ptr, int n)
{
    __shared__ int buf[1024];
    __shared__ int carry;
    if (threadIdx.x == 0) carry = 0;
    __syncthreads();
    for (int base = 0; base < n; base += 1024) {
        int i = base + (int)threadIdx.x;
        int v = (i < n) ? cnt[i] : 0;
        buf[threadIdx.x] = v;
        __syncthreads();
        for (int off = 1; off < 1024; off <<= 1) {
            int t = (threadIdx.x >= off) ? buf[threadIdx.x - off] : 0;
            __syncthreads();
            buf[threadIdx.x] += t;
            __syncthreads();
        }
        if (i < n) ptr[i] = carry + buf[threadIdx.x] - v;   // exclusive
        __syncthreads();
        if (threadIdx.x == 1023) carry += buf[1023];
        __syncthreads();
    }
    if (threadIdx.x == 0) ptr[n] = carry;
}

__global__ void fill_kernel(const int* __restrict__ ei, int E,
                            const int* __restrict__ ptr, int* __restrict__ fill,
                            const float* __restrict__ dis,
                            int* __restrict__ adj, float* __restrict__ wn)
{
    int e = blockIdx.x * blockDim.x + threadIdx.x;
    if (e >= E) return;
    int r = ei[e];
    int c = ei[E + e];
    int pos = atomicAdd(&fill[c], 1);
    int idx = ptr[c] + pos;
    adj[idx] = r;
    wn[idx] = dis[r] * dis[c];
}

// ---------------- K-hop propagation: one wave per node, lane = class --------
__global__ __launch_bounds__(256) void prop_kernel(
    const float* __restrict__ hin, float* __restrict__ hout,
    float* __restrict__ hidden,
    const int* __restrict__ ptr, const int* __restrict__ adj,
    const float* __restrict__ wn, const float* __restrict__ dis,
    const float* __restrict__ temp, int k, int Nn)
{
    const int wave = threadIdx.x >> 6;
    const int lane = threadIdx.x & 63;
    const int v = blockIdx.x * 4 + wave;
    if (v >= Nn) return;

    const int beg = ptr[v], end = ptr[v + 1];
    const float d = dis[v];
    float acc0 = d * d * hin[(long)v * NCLS + lane];   // self loop
    float acc1 = 0.f;
    int e = beg;
    for (; e + 1 < end; e += 2) {
        int u0 = adj[e], u1 = adj[e + 1];
        float w0 = wn[e], w1 = wn[e + 1];
        acc0 = fmaf(w0, hin[(long)u0 * NCLS + lane], acc0);
        acc1 = fmaf(w1, hin[(long)u1 * NCLS + lane], acc1);
    }
    if (e < end) acc0 = fmaf(wn[e], hin[(long)adj[e] * NCLS + lane], acc0);

    float acc = acc0 + acc1;
    long idx = (long)v * NCLS + lane;
    hout[idx] = acc;
    hidden[idx] += temp[k + 1] * acc;
}

// ---------------- log-softmax: one wave per node ----------------
__global__ __launch_bounds__(256) void lsm_kernel(const float* __restrict__ hidden,
                                                  float* __restrict__ out, int Nn)
{
    const int wave = threadIdx.x >> 6;
    const int lane = threadIdx.x & 63;
    const int v = blockIdx.x * 4 + wave;
    if (v >= Nn) return;
    float x = hidden[(long)v * NCLS + lane];
    float m = x;
    #pragma unroll
    for (int off = 32; off > 0; off >>= 1) m = fmaxf(m, __shfl_xor(m, off));
    float s = __expf(x - m);
    #pragma unroll
    for (int off = 32; off > 0; off >>= 1) s += __shfl_xor(s, off);
    out[(long)v * NCLS + lane] = x - m - logf(s);
}

// ---------------- launcher ----------------
extern "C" void kernel_launch(void* const* d_in, const int* in_sizes, int n_in,
                              void* d_out, int out_size, void* d_ws, size_t ws_size,
                              hipStream_t stream)
{
    const float* x    = (const float*)d_in[0];
    const int*   ei   = (const int*)  d_in[1];
    const float* W1   = (const float*)d_in[2];
    const float* b1   = (const float*)d_in[3];
    const float* W2   = (const float*)d_in[4];
    const float* b2   = (const float*)d_in[5];
    const float* temp = (const float*)d_in[6];

    const int Nn = in_sizes[0] / NFEAT;   // 100000
    const int E  = in_sizes[1] / 2;       // 3200000

    // workspace layout (bytes)
    char* ws = (char*)d_ws;
    size_t off = 0;
    auto alloc = [&](size_t bytes) { size_t o = off; off += (bytes + 255) & ~255ull; return o; };

    size_t hmid_off   = alloc((size_t)Nn * NHID * 4);   // 102.4 MB — reused below
    size_t hA_off     = alloc((size_t)Nn * NCLS * 4);
    size_t hidden_off = alloc((size_t)Nn * NCLS * 4);
    size_t cnt_off    = alloc((size_t)Nn * 4);
    size_t fill_off   = alloc((size_t)Nn * 4);
    size_t dis_off    = alloc((size_t)Nn * 4);
    size_t ptr_off    = alloc((size_t)(Nn + 1) * 4);

    float* hmid   = (float*)(ws + hmid_off);
    float* hA     = (float*)(ws + hA_off);
    float* hidden = (float*)(ws + hidden_off);
    int*   cnt    = (int*)  (ws + cnt_off);
    int*   fillb  = (int*)  (ws + fill_off);
    float* dis    = (float*)(ws + dis_off);
    int*   ptr    = (int*)  (ws + ptr_off);
    // reuse hmid region after the MLP finishes: adj | wn | hB  (51.2 MB <= 102.4 MB)
    int*   adj = (int*)  (ws + hmid_off);
    float* wn  = (float*)(ws + hmid_off + (size_t)E * 4);
    float* hB  = (float*)(ws + hmid_off + (size_t)E * 8);

    // ---- MLP ----
    {
        dim3 g((Nn + BM - 1) / BM, NHID / BN);
        gemm_kernel<0><<<g, 256, 0, stream>>>(x, W1, b1, hmid, Nn, NHID, NFEAT, nullptr, nullptr);
    }
    {
        dim3 g((Nn + BM - 1) / BM, NCLS / BN);
        gemm_kernel<1><<<g, 256, 0, stream>>>(hmid, W2, b2, hA, Nn, NCLS, NHID, hidden, temp);
    }

    // ---- CSR build (reuses hmid space for adj/wn) ----
    hipMemsetAsync(cnt,   0, (size_t)Nn * 4, stream);
    hipMemsetAsync(fillb, 0, (size_t)Nn * 4, stream);
    {
        int g = (E + 255) / 256;
        count_kernel<<<g, 256, 0, stream>>>(ei, E, cnt);
    }
    dis_kernel<<<(Nn + 255) / 256, 256, 0, stream>>>(cnt, dis, Nn);
    scan_kernel<<<1, 1024, 0, stream>>>(cnt, ptr, Nn);
    fill_kernel<<<(E + 255) / 256, 256, 0, stream>>>(ei, E, ptr, fillb, dis, adj, wn);

    // ---- K-hop propagation ----
    int pg = (Nn + 3) / 4;
    for (int k = 0; k < KHOP; k++) {
        const float* hin = (k & 1) ? hB : hA;
        float*       ho  = (k & 1) ? hA : hB;
        prop_kernel<<<pg, 256, 0, stream>>>(hin, ho, hidden, ptr, adj, wn, dis, temp, k, Nn);
    }

    // ---- log-softmax ----
    lsm_kernel<<<pg, 256, 0, stream>>>(hidden, (float*)d_out, Nn);
}

// Round 2
// 2388.954 us; speedup vs baseline: 1.2119x; 1.2119x over previous
//
#include <hip/hip_runtime.h>
#include <math.h>

#define NFEAT 512
#define NHID  256
#define NCLS  64
#define KHOP  10
#define LDSTRIDE 56   // bf16 elems; 112B rows -> 16B aligned, 2-way bank alias (free)

typedef __attribute__((ext_vector_type(8))) short short8;
typedef __attribute__((ext_vector_type(4))) float f32x4;

__device__ __forceinline__ unsigned short f2bf(float f) {
    unsigned u = __float_as_uint(f);
    u += 0x7FFFu + ((u >> 16) & 1u);       // RNE
    return (unsigned short)(u >> 16);
}
__device__ __forceinline__ float bf2f(unsigned short h) {
    return __uint_as_float((unsigned)h << 16);
}

// ---------------- casts ----------------
__global__ __launch_bounds__(256) void cast_kernel(const float* __restrict__ src,
                                                   unsigned short* __restrict__ dst, long n)
{
    long i = (long)blockIdx.x * 1024 + (long)threadIdx.x * 4;
    if (i + 3 < n) {
        float4 v = *(const float4*)(src + i);
        dst[i+0] = f2bf(v.x); dst[i+1] = f2bf(v.y);
        dst[i+2] = f2bf(v.z); dst[i+3] = f2bf(v.w);
    } else {
        for (int j = 0; j < 4 && i + j < n; j++) dst[i+j] = f2bf(src[i+j]);
    }
}

// src [K][N] fp32 -> dst [N][K] bf16 (transpose-cast, tiny matrices)
__global__ __launch_bounds__(256) void castT_kernel(const float* __restrict__ src,
                                                    unsigned short* __restrict__ dst,
                                                    int K, int N)
{
    int i = blockIdx.x * 256 + threadIdx.x;
    if (i < K * N) {
        int k = i / N, n = i % N;
        dst[(long)n * K + k] = f2bf(src[i]);
    }
}

// ---------------- MFMA GEMM1: hmid = relu(x @ W1 + b1), bf16 in/out ----------
// A [M][512] bf16, BT = W1^T [256][512] bf16, C [M][256] bf16
__global__ __launch_bounds__(256) void mfma_gemm1(
    const unsigned short* __restrict__ A, const unsigned short* __restrict__ BT,
    const float* __restrict__ bias, unsigned short* __restrict__ C, int M)
{
    __shared__ unsigned short As[128 * LDSTRIDE];
    __shared__ unsigned short Bs[128 * LDSTRIDE];
    const int tid = threadIdx.x;
    const int wave = tid >> 6, lane = tid & 63;
    const int quad = lane >> 4, l16 = lane & 15;
    const int wm = wave >> 1, wn = wave & 1;
    const int m0 = blockIdx.x * 128, n0 = blockIdx.y * 128;

    f32x4 acc[4][4] = {};
    const int srow = tid >> 2;           // 0..63
    const int schunk = (tid & 3) * 8;    // 0,8,16,24 (bf16 elems)

    for (int k0 = 0; k0 < NFEAT; k0 += 32) {
        #pragma unroll
        for (int i = 0; i < 2; i++) {
            int r = srow + i * 64;
            int rg = m0 + r;
            short8 v = {};
            if (rg < M) v = *(const short8*)(A + (long)rg * NFEAT + k0 + schunk);
            *(short8*)(As + r * LDSTRIDE + schunk) = v;
        }
        #pragma unroll
        for (int i = 0; i < 2; i++) {
            int r = srow + i * 64;
            short8 v = *(const short8*)(BT + (long)(n0 + r) * NFEAT + k0 + schunk);
            *(short8*)(Bs + r * LDSTRIDE + schunk) = v;
        }
        __syncthreads();
        short8 af[4], bfr[4];
        #pragma unroll
        for (int mi = 0; mi < 4; mi++)
            af[mi] = *(const short8*)(As + (wm*64 + mi*16 + l16) * LDSTRIDE + quad*8);
        #pragma unroll
        for (int nj = 0; nj < 4; nj++)
            bfr[nj] = *(const short8*)(Bs + (wn*64 + nj*16 + l16) * LDSTRIDE + quad*8);
        #pragma unroll
        for (int mi = 0; mi < 4; mi++)
            #pragma unroll
            for (int nj = 0; nj < 4; nj++)
                acc[mi][nj] = __builtin_amdgcn_mfma_f32_16x16x32_bf16(af[mi], bfr[nj], acc[mi][nj], 0, 0, 0);
        __syncthreads();
    }

    #pragma unroll
    for (int mi = 0; mi < 4; mi++)
        #pragma unroll
        for (int r = 0; r < 4; r++) {
            int row = m0 + wm*64 + mi*16 + quad*4 + r;   // C/D: row = quad*4+reg
            if (row >= M) continue;
            #pragma unroll
            for (int nj = 0; nj < 4; nj++) {
                int col = n0 + wn*64 + nj*16 + l16;      // C/D: col = lane&15
                float v = acc[mi][nj][r] + bias[col];
                C[(long)row * NHID + col] = f2bf(fmaxf(v, 0.f));
            }
        }
}

// ---------------- MFMA GEMM2: hA = hmid @ W2 + b2; hidden = temp0*hA ---------
__global__ __launch_bounds__(256) void mfma_gemm2(
    const unsigned short* __restrict__ A, const unsigned short* __restrict__ BT,
    const float* __restrict__ bias, unsigned short* __restrict__ C,
    float* __restrict__ hidden, const float* __restrict__ temp, int M)
{
    __shared__ unsigned short As[128 * LDSTRIDE];
    __shared__ unsigned short Bs[64 * LDSTRIDE];
    const int tid = threadIdx.x;
    const int wave = tid >> 6, lane = tid & 63;
    const int quad = lane >> 4, l16 = lane & 15;
    const int m0 = blockIdx.x * 128;
    const float t0 = temp[0];

    f32x4 acc[2][4] = {};
    const int srow = tid >> 2;
    const int schunk = (tid & 3) * 8;

    for (int k0 = 0; k0 < NHID; k0 += 32) {
        #pragma unroll
        for (int i = 0; i < 2; i++) {
            int r = srow + i * 64;
            int rg = m0 + r;
            short8 v = {};
            if (rg < M) v = *(const short8*)(A + (long)rg * NHID + k0 + schunk);
            *(short8*)(As + r * LDSTRIDE + schunk) = v;
        }
        {
            short8 v = *(const short8*)(BT + (long)srow * NHID + k0 + schunk);
            *(short8*)(Bs + srow * LDSTRIDE + schunk) = v;
        }
        __syncthreads();
        short8 af[2], bfr[4];
        #pragma unroll
        for (int mi = 0; mi < 2; mi++)
            af[mi] = *(const short8*)(As + (wave*32 + mi*16 + l16) * LDSTRIDE + quad*8);
        #pragma unroll
        for (int nj = 0; nj < 4; nj++)
            bfr[nj] = *(const short8*)(Bs + (nj*16 + l16) * LDSTRIDE + quad*8);
        #pragma unroll
        for (int mi = 0; mi < 2; mi++)
            #pragma unroll
            for (int nj = 0; nj < 4; nj++)
                acc[mi][nj] = __builtin_amdgcn_mfma_f32_16x16x32_bf16(af[mi], bfr[nj], acc[mi][nj], 0, 0, 0);
        __syncthreads();
    }

    #pragma unroll
    for (int mi = 0; mi < 2; mi++)
        #pragma unroll
        for (int r = 0; r < 4; r++) {
            int row = m0 + wave*32 + mi*16 + quad*4 + r;
            if (row >= M) continue;
            #pragma unroll
            for (int nj = 0; nj < 4; nj++) {
                int col = nj*16 + l16;
                float v = acc[mi][nj][r] + bias[col];
                long idx = (long)row * NCLS + col;
                C[idx] = f2bf(v);
                hidden[idx] = t0 * v;
            }
        }
}

// ---------------- graph preprocessing ----------------
__global__ void count_kernel(const int* __restrict__ ei, int E, int* __restrict__ cnt)
{
    int e = blockIdx.x * blockDim.x + threadIdx.x;
    if (e < E) atomicAdd(&cnt[ei[E + e]], 1);
}

__global__ void dis_kernel(const int* __restrict__ cnt, float* __restrict__ dis, int Nn)
{
    int v = blockIdx.x * blockDim.x + threadIdx.x;
    if (v < Nn) dis[v] = rsqrtf((float)(cnt[v] + 1));
}

__global__ __launch_bounds__(256) void bsum_kernel(const int* __restrict__ cnt, int n,
                                                   int* __restrict__ bsum)
{
    __shared__ int ws[4];
    int i = blockIdx.x * 256 + threadIdx.x;
    int v = (i < n) ? cnt[i] : 0;
    #pragma unroll
    for (int off = 1; off < 64; off <<= 1) v += __shfl_xor(v, off);
    if ((threadIdx.x & 63) == 0) ws[threadIdx.x >> 6] = v;
    __syncthreads();
    if (threadIdx.x == 0) bsum[blockIdx.x] = ws[0] + ws[1] + ws[2] + ws[3];
}

__global__ __launch_bounds__(512) void bscan_kernel(int* __restrict__ bsum, int nb)
{
    __shared__ int buf[512];
    int i = threadIdx.x;
    int v = (i < nb) ? bsum[i] : 0;
    buf[i] = v;
    __syncthreads();
    for (int off = 1; off < 512; off <<= 1) {
        int t = (i >= off) ? buf[i - off] : 0;
        __syncthreads();
        buf[i] += t;
        __syncthreads();
    }
    if (i < nb) bsum[i] = buf[i] - v;   // exclusive
}

__global__ __launch_bounds__(256) void pscan_kernel(const int* __restrict__ cnt, int n,
                                                    const int* __restrict__ bsum,
                                                    int* __restrict__ ptr, int E)
{
    __shared__ int buf[256];
    int i = blockIdx.x * 256 + threadIdx.x;
    int v = (i < n) ? cnt[i] : 0;
    buf[threadIdx.x] = v;
    __syncthreads();
    for (int off = 1; off < 256; off <<= 1) {
        int t = (threadIdx.x >= off) ? buf[threadIdx.x - off] : 0;
        __syncthreads();
        buf[threadIdx.x] += t;
        __syncthreads();
    }
    if (i < n) ptr[i] = bsum[blockIdx.x] + buf[threadIdx.x] - v;
    if (i == 0) ptr[n] = E;
}

__global__ void fill_kernel(const int* __restrict__ ei, int E,
                            const int* __restrict__ ptr, int* __restrict__ fill,
                            const float* __restrict__ dis,
                            int* __restrict__ adj, float* __restrict__ wn)
{
    int e = blockIdx.x * blockDim.x + threadIdx.x;
    if (e >= E) return;
    int r = ei[e];
    int c = ei[E + e];
    int pos = atomicAdd(&fill[c], 1);
    int idx = ptr[c] + pos;
    adj[idx] = r;
    wn[idx] = dis[r] * dis[c];
}

// ---------------- K-hop propagation: one wave/node, lane=class, bf16 h ------
__global__ __launch_bounds__(256) void prop_kernel(
    const unsigned short* __restrict__ hin, unsigned short* __restrict__ hout,
    float* __restrict__ hidden,
    const int* __restrict__ ptr, const int* __restrict__ adj,
    const float* __restrict__ wn, const float* __restrict__ dis,
    const float* __restrict__ temp, int k, int Nn)
{
    const int wave = threadIdx.x >> 6, lane = threadIdx.x & 63;
    const int v = blockIdx.x * 4 + wave;
    if (v >= Nn) return;

    const int beg = ptr[v], end = ptr[v + 1];
    const float d = dis[v];
    float acc0 = d * d * bf2f(hin[(long)v * NCLS + lane]);
    float acc1 = 0.f;
    int e = beg;
    for (; e + 1 < end; e += 2) {
        int u0 = adj[e], u1 = adj[e + 1];
        float w0 = wn[e], w1 = wn[e + 1];
        acc0 = fmaf(w0, bf2f(hin[(long)u0 * NCLS + lane]), acc0);
        acc1 = fmaf(w1, bf2f(hin[(long)u1 * NCLS + lane]), acc1);
    }
    if (e < end) acc0 = fmaf(wn[e], bf2f(hin[(long)adj[e] * NCLS + lane]), acc0);

    float acc = acc0 + acc1;
    long idx = (long)v * NCLS + lane;
    hout[idx] = f2bf(acc);
    hidden[idx] += temp[k + 1] * acc;
}

// ---------------- log-softmax ----------------
__global__ __launch_bounds__(256) void lsm_kernel(const float* __restrict__ hidden,
                                                  float* __restrict__ out, int Nn)
{
    const int wave = threadIdx.x >> 6, lane = threadIdx.x & 63;
    const int v = blockIdx.x * 4 + wave;
    if (v >= Nn) return;
    float x = hidden[(long)v * NCLS + lane];
    float m = x;
    #pragma unroll
    for (int off = 32; off > 0; off >>= 1) m = fmaxf(m, __shfl_xor(m, off));
    float s = __expf(x - m);
    #pragma unroll
    for (int off = 32; off > 0; off >>= 1) s += __shfl_xor(s, off);
    out[(long)v * NCLS + lane] = x - m - logf(s);
}

// ---------------- launcher ----------------
extern "C" void kernel_launch(void* const* d_in, const int* in_sizes, int n_in,
                              void* d_out, int out_size, void* d_ws, size_t ws_size,
                              hipStream_t stream)
{
    const float* x    = (const float*)d_in[0];
    const int*   ei   = (const int*)  d_in[1];
    const float* W1   = (const float*)d_in[2];
    const float* b1   = (const float*)d_in[3];
    const float* W2   = (const float*)d_in[4];
    const float* b2   = (const float*)d_in[5];
    const float* temp = (const float*)d_in[6];

    const int Nn = in_sizes[0] / NFEAT;   // 100000
    const int E  = in_sizes[1] / 2;       // 3200000

    char* ws = (char*)d_ws;
    size_t off = 0;
    auto alloc = [&](size_t bytes) { size_t o = off; off += (bytes + 255) & ~255ull; return o; };

    // region0: x_bf (102.4 MB), reused after GEMM1 for adj|wn|hA|hB|hidden (76.8 MB)
    size_t r0 = alloc((size_t)Nn * NFEAT * 2);
    size_t hmid_off = alloc((size_t)Nn * NHID * 2);     // 51.2 MB
    size_t w1t_off  = alloc((size_t)NFEAT * NHID * 2);
    size_t w2t_off  = alloc((size_t)NHID * NCLS * 2);
    size_t cnt_off  = alloc((size_t)Nn * 4);
    size_t fill_off = alloc((size_t)Nn * 4);
    size_t dis_off  = alloc((size_t)Nn * 4);
    size_t ptr_off  = alloc((size_t)(Nn + 1) * 4);
    size_t bsum_off = alloc(((size_t)Nn / 256 + 2) * 4);

    unsigned short* x_bf  = (unsigned short*)(ws + r0);
    unsigned short* hmid  = (unsigned short*)(ws + hmid_off);
    unsigned short* W1T   = (unsigned short*)(ws + w1t_off);
    unsigned short* W2T   = (unsigned short*)(ws + w2t_off);
    int*   cnt   = (int*)  (ws + cnt_off);
    int*   fillb = (int*)  (ws + fill_off);
    float* dis   = (float*)(ws + dis_off);
    int*   ptr   = (int*)  (ws + ptr_off);
    int*   bsum  = (int*)  (ws + bsum_off);

    // region0 reuse (after gemm1 consumed x_bf):
    int*            adj    = (int*)           (ws + r0);
    float*          wn     = (float*)         (ws + r0 + (size_t)E * 4);
    unsigned short* hA     = (unsigned short*)(ws + r0 + (size_t)E * 8);
    unsigned short* hB     = (unsigned short*)(ws + r0 + (size_t)E * 8 + (size_t)Nn * NCLS * 2);
    float*          hidden = (float*)         (ws + r0 + (size_t)E * 8 + (size_t)Nn * NCLS * 4);

    // ---- casts ----
    cast_kernel<<<(int)(((long)Nn * NFEAT + 1023) / 1024), 256, 0, stream>>>(x, x_bf, (long)Nn * NFEAT);
    castT_kernel<<<(NFEAT * NHID + 255) / 256, 256, 0, stream>>>(W1, W1T, NFEAT, NHID);
    castT_kernel<<<(NHID * NCLS + 255) / 256, 256, 0, stream>>>(W2, W2T, NHID, NCLS);

    // ---- GEMM1 (consumes x_bf) ----
    {
        dim3 g((Nn + 127) / 128, NHID / 128);
        mfma_gemm1<<<g, 256, 0, stream>>>(x_bf, W1T, b1, hmid, Nn);
    }

    // ---- CSR build (now x_bf region is dead; adj/wn live there) ----
    hipMemsetAsync(cnt,   0, (size_t)Nn * 4, stream);
    hipMemsetAsync(fillb, 0, (size_t)Nn * 4, stream);
    count_kernel<<<(E + 255) / 256, 256, 0, stream>>>(ei, E, cnt);
    dis_kernel<<<(Nn + 255) / 256, 256, 0, stream>>>(cnt, dis, Nn);
    int nb = (Nn + 255) / 256;
    bsum_kernel<<<nb, 256, 0, stream>>>(cnt, Nn, bsum);
    bscan_kernel<<<1, 512, 0, stream>>>(bsum, nb);
    pscan_kernel<<<nb, 256, 0, stream>>>(cnt, Nn, bsum, ptr, E);
    fill_kernel<<<(E + 255) / 256, 256, 0, stream>>>(ei, E, ptr, fillb, dis, adj, wn);

    // ---- GEMM2 (writes hA bf16 + hidden fp32) ----
    mfma_gemm2<<<(Nn + 127) / 128, 256, 0, stream>>>(hmid, W2T, b2, hA, hidden, temp, Nn);

    // ---- K-hop propagation ----
    int pg = (Nn + 3) / 4;
    for (int k = 0; k < KHOP; k++) {
        const unsigned short* hin = (k & 1) ? hB : hA;
        unsigned short*       ho  = (k & 1) ? hA : hB;
        prop_kernel<<<pg, 256, 0, stream>>>(hin, ho, hidden, ptr, adj, wn, dis, temp, k, Nn);
    }

    // ---- log-softmax ----
    lsm_kernel<<<pg, 256, 0, stream>>>(hidden, (float*)d_out, Nn);
}

// Round 3
// 1413.987 us; speedup vs baseline: 2.0476x; 1.6895x over previous
//
#include <hip/hip_runtime.h>
#include <math.h>

#define NFEAT 512
#define NHID  256
#define NCLS  64
#define KHOP  10
#define LDSTRIDE 56   // bf16 elems; 112B rows -> 16B aligned, 2-way bank alias (free)

typedef __attribute__((ext_vector_type(8))) short short8;
typedef __attribute__((ext_vector_type(4))) float f32x4;

__device__ __forceinline__ unsigned short f2bf(float f) {
    unsigned u = __float_as_uint(f);
    u += 0x7FFFu + ((u >> 16) & 1u);       // RNE
    return (unsigned short)(u >> 16);
}
__device__ __forceinline__ float bf2f(unsigned short h) {
    return __uint_as_float((unsigned)h << 16);
}

// ---------------- casts ----------------
__global__ __launch_bounds__(256) void cast_kernel(const float* __restrict__ src,
                                                   unsigned short* __restrict__ dst, long n)
{
    long i = (long)blockIdx.x * 1024 + (long)threadIdx.x * 4;
    if (i + 3 < n) {
        float4 v = *(const float4*)(src + i);
        dst[i+0] = f2bf(v.x); dst[i+1] = f2bf(v.y);
        dst[i+2] = f2bf(v.z); dst[i+3] = f2bf(v.w);
    } else {
        for (int j = 0; j < 4 && i + j < n; j++) dst[i+j] = f2bf(src[i+j]);
    }
}

// src [K][N] fp32 -> dst [N][K] bf16 (transpose-cast, tiny matrices)
__global__ __launch_bounds__(256) void castT_kernel(const float* __restrict__ src,
                                                    unsigned short* __restrict__ dst,
                                                    int K, int N)
{
    int i = blockIdx.x * 256 + threadIdx.x;
    if (i < K * N) {
        int k = i / N, n = i % N;
        dst[(long)n * K + k] = f2bf(src[i]);
    }
}

// ---------------- MFMA GEMM1: hmid = relu(x @ W1 + b1), bf16 in/out ----------
__global__ __launch_bounds__(256) void mfma_gemm1(
    const unsigned short* __restrict__ A, const unsigned short* __restrict__ BT,
    const float* __restrict__ bias, unsigned short* __restrict__ C, int M)
{
    __shared__ unsigned short As[128 * LDSTRIDE];
    __shared__ unsigned short Bs[128 * LDSTRIDE];
    const int tid = threadIdx.x;
    const int wave = tid >> 6, lane = tid & 63;
    const int quad = lane >> 4, l16 = lane & 15;
    const int wm = wave >> 1, wn = wave & 1;
    const int m0 = blockIdx.x * 128, n0 = blockIdx.y * 128;

    f32x4 acc[4][4] = {};
    const int srow = tid >> 2;           // 0..63
    const int schunk = (tid & 3) * 8;    // 0,8,16,24 (bf16 elems)

    for (int k0 = 0; k0 < NFEAT; k0 += 32) {
        #pragma unroll
        for (int i = 0; i < 2; i++) {
            int r = srow + i * 64;
            int rg = m0 + r;
            short8 v = {};
            if (rg < M) v = *(const short8*)(A + (long)rg * NFEAT + k0 + schunk);
            *(short8*)(As + r * LDSTRIDE + schunk) = v;
        }
        #pragma unroll
        for (int i = 0; i < 2; i++) {
            int r = srow + i * 64;
            short8 v = *(const short8*)(BT + (long)(n0 + r) * NFEAT + k0 + schunk);
            *(short8*)(Bs + r * LDSTRIDE + schunk) = v;
        }
        __syncthreads();
        short8 af[4], bfr[4];
        #pragma unroll
        for (int mi = 0; mi < 4; mi++)
            af[mi] = *(const short8*)(As + (wm*64 + mi*16 + l16) * LDSTRIDE + quad*8);
        #pragma unroll
        for (int nj = 0; nj < 4; nj++)
            bfr[nj] = *(const short8*)(Bs + (wn*64 + nj*16 + l16) * LDSTRIDE + quad*8);
        #pragma unroll
        for (int mi = 0; mi < 4; mi++)
            #pragma unroll
            for (int nj = 0; nj < 4; nj++)
                acc[mi][nj] = __builtin_amdgcn_mfma_f32_16x16x32_bf16(af[mi], bfr[nj], acc[mi][nj], 0, 0, 0);
        __syncthreads();
    }

    #pragma unroll
    for (int mi = 0; mi < 4; mi++)
        #pragma unroll
        for (int r = 0; r < 4; r++) {
            int row = m0 + wm*64 + mi*16 + quad*4 + r;
            if (row >= M) continue;
            #pragma unroll
            for (int nj = 0; nj < 4; nj++) {
                int col = n0 + wn*64 + nj*16 + l16;
                float v = acc[mi][nj][r] + bias[col];
                C[(long)row * NHID + col] = f2bf(fmaxf(v, 0.f));
            }
        }
}

// ------- MFMA GEMM2: v = hmid@W2 + b2; s0 = bf16(dis*v); hidden = temp0*v ----
__global__ __launch_bounds__(256) void mfma_gemm2(
    const unsigned short* __restrict__ A, const unsigned short* __restrict__ BT,
    const float* __restrict__ bias, unsigned short* __restrict__ S,
    float* __restrict__ hidden, const float* __restrict__ temp,
    const float* __restrict__ dis, int M)
{
    __shared__ unsigned short As[128 * LDSTRIDE];
    __shared__ unsigned short Bs[64 * LDSTRIDE];
    const int tid = threadIdx.x;
    const int wave = tid >> 6, lane = tid & 63;
    const int quad = lane >> 4, l16 = lane & 15;
    const int m0 = blockIdx.x * 128;
    const float t0 = temp[0];

    f32x4 acc[2][4] = {};
    const int srow = tid >> 2;
    const int schunk = (tid & 3) * 8;

    for (int k0 = 0; k0 < NHID; k0 += 32) {
        #pragma unroll
        for (int i = 0; i < 2; i++) {
            int r = srow + i * 64;
            int rg = m0 + r;
            short8 v = {};
            if (rg < M) v = *(const short8*)(A + (long)rg * NHID + k0 + schunk);
            *(short8*)(As + r * LDSTRIDE + schunk) = v;
        }
        {
            short8 v = *(const short8*)(BT + (long)srow * NHID + k0 + schunk);
            *(short8*)(Bs + srow * LDSTRIDE + schunk) = v;
        }
        __syncthreads();
        short8 af[2], bfr[4];
        #pragma unroll
        for (int mi = 0; mi < 2; mi++)
            af[mi] = *(const short8*)(As + (wave*32 + mi*16 + l16) * LDSTRIDE + quad*8);
        #pragma unroll
        for (int nj = 0; nj < 4; nj++)
            bfr[nj] = *(const short8*)(Bs + (nj*16 + l16) * LDSTRIDE + quad*8);
        #pragma unroll
        for (int mi = 0; mi < 2; mi++)
            #pragma unroll
            for (int nj = 0; nj < 4; nj++)
                acc[mi][nj] = __builtin_amdgcn_mfma_f32_16x16x32_bf16(af[mi], bfr[nj], acc[mi][nj], 0, 0, 0);
        __syncthreads();
    }

    #pragma unroll
    for (int mi = 0; mi < 2; mi++)
        #pragma unroll
        for (int r = 0; r < 4; r++) {
            int row = m0 + wave*32 + mi*16 + quad*4 + r;
            if (row >= M) continue;
            float dr = dis[row];
            #pragma unroll
            for (int nj = 0; nj < 4; nj++) {
                int col = nj*16 + l16;
                float v = acc[mi][nj][r] + bias[col];
                long idx = (long)row * NCLS + col;
                S[idx] = f2bf(dr * v);
                hidden[idx] = t0 * v;
            }
        }
}

// ---------------- graph preprocessing ----------------
__global__ void count_kernel(const int* __restrict__ ei, int E, int* __restrict__ cnt)
{
    int e = blockIdx.x * blockDim.x + threadIdx.x;
    if (e < E) atomicAdd(&cnt[ei[E + e]], 1);
}

__global__ void dis_kernel(const int* __restrict__ cnt, float* __restrict__ dis, int Nn)
{
    int v = blockIdx.x * blockDim.x + threadIdx.x;
    if (v < Nn) dis[v] = rsqrtf((float)(cnt[v] + 1));
}

// block sums of padded counts (pad each node's degree to multiple of 8)
__global__ __launch_bounds__(256) void bsum_kernel(const int* __restrict__ cnt, int n,
                                                   int* __restrict__ bsum)
{
    __shared__ int ws[4];
    int i = blockIdx.x * 256 + threadIdx.x;
    int v = (i < n) ? ((cnt[i] + 7) & ~7) : 0;
    #pragma unroll
    for (int off = 1; off < 64; off <<= 1) v += __shfl_xor(v, off);
    if ((threadIdx.x & 63) == 0) ws[threadIdx.x >> 6] = v;
    __syncthreads();
    if (threadIdx.x == 0) bsum[blockIdx.x] = ws[0] + ws[1] + ws[2] + ws[3];
}

__global__ __launch_bounds__(512) void bscan_kernel(int* __restrict__ bsum, int nb)
{
    __shared__ int buf[512];
    int i = threadIdx.x;
    int v = (i < nb) ? bsum[i] : 0;
    buf[i] = v;
    __syncthreads();
    for (int off = 1; off < 512; off <<= 1) {
        int t = (i >= off) ? buf[i - off] : 0;
        __syncthreads();
        buf[i] += t;
        __syncthreads();
    }
    if (i < nb) bsum[i] = buf[i] - v;   // exclusive
}

__global__ __launch_bounds__(256) void pscan_kernel(const int* __restrict__ cnt, int n,
                                                    const int* __restrict__ bsum,
                                                    int* __restrict__ ptr)
{
    __shared__ int buf[256];
    int i = blockIdx.x * 256 + threadIdx.x;
    int v = (i < n) ? ((cnt[i] + 7) & ~7) : 0;
    buf[threadIdx.x] = v;
    __syncthreads();
    for (int off = 1; off < 256; off <<= 1) {
        int t = (threadIdx.x >= off) ? buf[threadIdx.x - off] : 0;
        __syncthreads();
        buf[threadIdx.x] += t;
        __syncthreads();
    }
    if (i < n) ptr[i] = bsum[blockIdx.x] + buf[threadIdx.x] - v;
    if (i == n - 1) ptr[n] = bsum[blockIdx.x] + buf[threadIdx.x];   // total padded
}

__global__ void fill_kernel(const int* __restrict__ ei, int E,
                            const int* __restrict__ ptr, int* __restrict__ fill,
                            int* __restrict__ adj)
{
    int e = blockIdx.x * blockDim.x + threadIdx.x;
    if (e >= E) return;
    int r = ei[e];
    int c = ei[E + e];
    int pos = atomicAdd(&fill[c], 1);
    adj[ptr[c] + pos] = r;
}

// pad each node's CSR tail with the dummy node id Nn (whose s-row is zero)
__global__ void padfill_kernel(const int* __restrict__ cnt, const int* __restrict__ ptr,
                               int* __restrict__ adj, int Nn)
{
    int v = blockIdx.x * 256 + threadIdx.x;
    if (v >= Nn) return;
    int b = ptr[v] + cnt[v], e = ptr[v + 1];
    for (int i = b; i < e; i++) adj[i] = Nn;
}

__global__ void zdum_kernel(unsigned short* __restrict__ sA,
                            unsigned short* __restrict__ sB, int Nn)
{
    int i = threadIdx.x;
    if (i < 64) sA[(long)Nn * NCLS + i] = 0;
    else        sB[(long)Nn * NCLS + (i - 64)] = 0;
}

// -------- K-hop propagation in s-space: one wave/node, lane=class -----------
// s_{k+1}[v] = d_v^2 * (s_k[v] + sum_{u in N(v)} s_k[u]);  hidden += temp*d_v*(...)
__global__ __launch_bounds__(256) void prop_kernel(
    const unsigned short* __restrict__ sin, unsigned short* __restrict__ sout,
    float* __restrict__ hidden,
    const int* __restrict__ ptr, const int* __restrict__ adj,
    const float* __restrict__ dis, const float* __restrict__ temp, int k, int Nn)
{
    const int wave = threadIdx.x >> 6, lane = threadIdx.x & 63;
    const int v = blockIdx.x * 4 + wave;
    if (v >= Nn) return;

    const int beg = ptr[v], end = ptr[v + 1];
    const float d = dis[v];
    float acc = bf2f(sin[v * NCLS + lane]);   // self loop term

    for (int e = beg; e < end; e += 8) {
        int4 u0 = *(const int4*)(adj + e);
        int4 u1 = *(const int4*)(adj + e + 4);
        float a0 = bf2f(sin[u0.x * NCLS + lane]);
        float a1 = bf2f(sin[u0.y * NCLS + lane]);
        float a2 = bf2f(sin[u0.z * NCLS + lane]);
        float a3 = bf2f(sin[u0.w * NCLS + lane]);
        float a4 = bf2f(sin[u1.x * NCLS + lane]);
        float a5 = bf2f(sin[u1.y * NCLS + lane]);
        float a6 = bf2f(sin[u1.z * NCLS + lane]);
        float a7 = bf2f(sin[u1.w * NCLS + lane]);
        acc += ((a0 + a1) + (a2 + a3)) + ((a4 + a5) + (a6 + a7));
    }

    int idx = v * NCLS + lane;
    float h = d * acc;
    hidden[idx] += temp[k + 1] * h;
    sout[idx] = f2bf(d * h);
}

// ---------------- log-softmax ----------------
__global__ __launch_bounds__(256) void lsm_kernel(const float* __restrict__ hidden,
                                                  float* __restrict__ out, int Nn)
{
    const int wave = threadIdx.x >> 6, lane = threadIdx.x & 63;
    const int v = blockIdx.x * 4 + wave;
    if (v >= Nn) return;
    float x = hidden[(long)v * NCLS + lane];
    float m = x;
    #pragma unroll
    for (int off = 32; off > 0; off >>= 1) m = fmaxf(m, __shfl_xor(m, off));
    float s = __expf(x - m);
    #pragma unroll
    for (int off = 32; off > 0; off >>= 1) s += __shfl_xor(s, off);
    out[(long)v * NCLS + lane] = x - m - logf(s);
}

// ---------------- launcher ----------------
extern "C" void kernel_launch(void* const* d_in, const int* in_sizes, int n_in,
                              void* d_out, int out_size, void* d_ws, size_t ws_size,
                              hipStream_t stream)
{
    const float* x    = (const float*)d_in[0];
    const int*   ei   = (const int*)  d_in[1];
    const float* W1   = (const float*)d_in[2];
    const float* b1   = (const float*)d_in[3];
    const float* W2   = (const float*)d_in[4];
    const float* b2   = (const float*)d_in[5];
    const float* temp = (const float*)d_in[6];

    const int Nn = in_sizes[0] / NFEAT;   // 100000
    const int E  = in_sizes[1] / 2;       // 3200000

    char* ws = (char*)d_ws;
    size_t off = 0;
    auto alloc = [&](size_t bytes) { size_t o = off; off += (bytes + 255) & ~255ull; return o; };

    // region0: x_bf (102.4 MB); after GEMM1 reused for adj|sA|sB|hidden (~67 MB)
    size_t r0 = alloc((size_t)Nn * NFEAT * 2);
    size_t hmid_off = alloc((size_t)Nn * NHID * 2);
    size_t w1t_off  = alloc((size_t)NFEAT * NHID * 2);
    size_t w2t_off  = alloc((size_t)NHID * NCLS * 2);
    size_t cnt_off  = alloc((size_t)Nn * 4);
    size_t fill_off = alloc((size_t)Nn * 4);
    size_t dis_off  = alloc((size_t)Nn * 4);
    size_t ptr_off  = alloc((size_t)(Nn + 1) * 4);
    size_t bsum_off = alloc(((size_t)Nn / 256 + 2) * 4);

    unsigned short* x_bf = (unsigned short*)(ws + r0);
    unsigned short* hmid = (unsigned short*)(ws + hmid_off);
    unsigned short* W1T  = (unsigned short*)(ws + w1t_off);
    unsigned short* W2T  = (unsigned short*)(ws + w2t_off);
    int*   cnt   = (int*)  (ws + cnt_off);
    int*   fillb = (int*)  (ws + fill_off);
    float* dis   = (float*)(ws + dis_off);
    int*   ptr   = (int*)  (ws + ptr_off);
    int*   bsum  = (int*)  (ws + bsum_off);

    // region0 reuse: padded adj (<= E + 8*Nn ints), sA, sB, hidden
    size_t Epad = (size_t)E + 8ull * Nn;
    int*            adj    = (int*)           (ws + r0);
    unsigned short* sA     = (unsigned short*)(ws + r0 + Epad * 4);
    unsigned short* sB     = (unsigned short*)(ws + r0 + Epad * 4 + (size_t)(Nn + 1) * NCLS * 2);
    float*          hidden = (float*)         (ws + r0 + Epad * 4 + (size_t)(Nn + 1) * NCLS * 4);

    // ---- casts ----
    cast_kernel<<<(int)(((long)Nn * NFEAT + 1023) / 1024), 256, 0, stream>>>(x, x_bf, (long)Nn * NFEAT);
    castT_kernel<<<(NFEAT * NHID + 255) / 256, 256, 0, stream>>>(W1, W1T, NFEAT, NHID);
    castT_kernel<<<(NHID * NCLS + 255) / 256, 256, 0, stream>>>(W2, W2T, NHID, NCLS);

    // ---- GEMM1 (consumes x_bf) ----
    {
        dim3 g((Nn + 127) / 128, NHID / 128);
        mfma_gemm1<<<g, 256, 0, stream>>>(x_bf, W1T, b1, hmid, Nn);
    }

    // ---- CSR build (x_bf region now dead; adj lives there) ----
    hipMemsetAsync(cnt,   0, (size_t)Nn * 4, stream);
    hipMemsetAsync(fillb, 0, (size_t)Nn * 4, stream);
    count_kernel<<<(E + 255) / 256, 256, 0, stream>>>(ei, E, cnt);
    dis_kernel<<<(Nn + 255) / 256, 256, 0, stream>>>(cnt, dis, Nn);
    int nb = (Nn + 255) / 256;
    bsum_kernel<<<nb, 256, 0, stream>>>(cnt, Nn, bsum);
    bscan_kernel<<<1, 512, 0, stream>>>(bsum, nb);
    pscan_kernel<<<nb, 256, 0, stream>>>(cnt, Nn, bsum, ptr);
    fill_kernel<<<(E + 255) / 256, 256, 0, stream>>>(ei, E, ptr, fillb, adj);
    padfill_kernel<<<(Nn + 255) / 256, 256, 0, stream>>>(cnt, ptr, adj, Nn);
    zdum_kernel<<<1, 128, 0, stream>>>(sA, sB, Nn);

    // ---- GEMM2 (writes s0 bf16 + hidden fp32; needs dis) ----
    mfma_gemm2<<<(Nn + 127) / 128, 256, 0, stream>>>(hmid, W2T, b2, sA, hidden, temp, dis, Nn);

    // ---- K-hop propagation ----
    int pg = (Nn + 3) / 4;
    for (int k = 0; k < KHOP; k++) {
        const unsigned short* sin = (k & 1) ? sB : sA;
        unsigned short*       so  = (k & 1) ? sA : sB;
        prop_kernel<<<pg, 256, 0, stream>>>(sin, so, hidden, ptr, adj, dis, temp, k, Nn);
    }

    // ---- log-softmax ----
    lsm_kernel<<<pg, 256, 0, stream>>>(hidden, (float*)d_out, Nn);
}